// Round 9
// baseline (349.475 us; speedup 1.0000x reference)
//
#include <hip/hip_runtime.h>

// Dtypes (rounds 1-6 forensics): floats fp32, edges int32 [E][2], output fp32.
// Workspace intermediates: bf16 (MFMA GEMM path).
// R6/R7 lesson: local arrays w/ MFMA failed SROA -> scratch. Named scalars only in GEMM.
// R8 lesson: named scalars fixed it (355->239us). R3/R4 crashes were edges-int64 OOB,
// NOT global_load_lds -> async staging reintroduced here (m97 rung, 517->874 TF).

typedef __bf16 bf16x8 __attribute__((ext_vector_type(8)));
typedef float  f32x4  __attribute__((ext_vector_type(4)));

__device__ __forceinline__ float bf2f(unsigned short u) {
    union { unsigned int i; float f; } v; v.i = ((unsigned int)u) << 16; return v.f;
}
__device__ __forceinline__ unsigned short f2bf(float f) {
    union { float f; unsigned int i; } v; v.f = f;
    unsigned int x = v.i;
    unsigned int r = (x + 0x7FFFu + ((x >> 16) & 1u)) >> 16;   // RNE
    return (unsigned short)r;
}
// async global->LDS DMA, 16B/lane; LDS dest = wave-uniform base + lane*16
__device__ __forceinline__ void async16(const unsigned short* g, unsigned short* l) {
    __builtin_amdgcn_global_load_lds(
        (const __attribute__((address_space(1))) unsigned int*)g,
        (__attribute__((address_space(3))) unsigned int*)l,
        16, 0, 0);
}

#define NNODE 20000
#define ROWS  40000      // B*N
#define DMODEL 256

// ---------- K0: fp32 weights -> bf16 transposed [n][k]; biases copied fp32 ----------
__global__ __launch_bounds__(256) void prep_kernel(
    const float* __restrict__ wq, const float* __restrict__ wk,
    const float* __restrict__ wv, const float* __restrict__ wo,
    const float* __restrict__ bq, const float* __restrict__ bk,
    const float* __restrict__ bv, const float* __restrict__ bo,
    unsigned short* __restrict__ Wqkvt,   // [768][256] bf16
    unsigned short* __restrict__ Wot,     // [256][256] bf16
    float* __restrict__ biasq,            // [768]
    float* __restrict__ biaso)            // [256]
{
    int idx = blockIdx.x * 256 + threadIdx.x;
    if (idx < 768 * 256) {
        int n = idx >> 8, k = idx & 255;
        int sel = n >> 8, nl = n & 255;
        const float* w = (sel == 0) ? wq : (sel == 1) ? wk : wv;
        Wqkvt[idx] = f2bf(w[k * 256 + nl]);
    } else {
        int idx2 = idx - 768 * 256;        // [0, 65536)
        int n = idx2 >> 8, k = idx2 & 255;
        Wot[idx2] = f2bf(wo[k * 256 + n]);
    }
    if (idx < 768) {
        const float* bb = (idx < 256) ? bq : (idx < 512) ? bk : bv;
        biasq[idx] = bb[idx & 255];
    }
    if (idx >= 768 && idx < 1024) biaso[idx - 768] = bo[idx - 768];
}

// ---------- K1: LayerNorm1 — half-wave (32 lanes) per row, 8 elems/lane; fp32 in, bf16 out ----------
__global__ __launch_bounds__(256) void ln1_kernel(
    const float* __restrict__ x,
    const float* __restrict__ g1, const float* __restrict__ b1,
    unsigned short* __restrict__ xn)
{
    int wave = threadIdx.x >> 6, lane = threadIdx.x & 63;
    int sub = lane >> 5, hl = lane & 31;
    int m = blockIdx.x * 8 + wave * 2 + sub;
    const float* xp = x + (size_t)m * DMODEL + hl * 8;
    float4 x0 = *(const float4*)xp;
    float4 x1 = *(const float4*)(xp + 4);
    float f[8] = {x0.x, x0.y, x0.z, x0.w, x1.x, x1.y, x1.z, x1.w};
    float s = 0.f, ss = 0.f;
    #pragma unroll
    for (int t = 0; t < 8; ++t) { s += f[t]; ss += f[t]*f[t]; }
    #pragma unroll
    for (int mk = 1; mk < 32; mk <<= 1) { s += __shfl_xor(s, mk); ss += __shfl_xor(ss, mk); }
    float mu  = s * (1.f/256.f);
    float var = ss * (1.f/256.f) - mu*mu;
    float rs  = rsqrtf(var + 1e-3f);
    float4 g0 = *(const float4*)(g1 + hl * 8);
    float4 g1v = *(const float4*)(g1 + hl * 8 + 4);
    float4 b0 = *(const float4*)(b1 + hl * 8);
    float4 b1v = *(const float4*)(b1 + hl * 8 + 4);
    float gg[8] = {g0.x, g0.y, g0.z, g0.w, g1v.x, g1v.y, g1v.z, g1v.w};
    float bb[8] = {b0.x, b0.y, b0.z, b0.w, b1v.x, b1v.y, b1v.z, b1v.w};
    unsigned short o[8];
    #pragma unroll
    for (int t = 0; t < 8; ++t) o[t] = f2bf((f[t] - mu) * rs * gg[t] + bb[t]);
    *(int4*)(xn + (size_t)m * DMODEL + hl * 8) = *(const int4*)o;
}

// ---------- K2/K4: bf16 MFMA GEMM, 128x128 tile, BK=32, ASYNC global_load_lds staging ----------
// C = A[M][256] @ Bt[Ncols][256]^T + bias.  EPI: relu + resid, write fp32; else bf16.
// LDS layout [row][32 shorts] UNPADDED — required by DMA lane mapping (uniform base + lane*16).
#define MFMA_BF16(d, a, b) d = __builtin_amdgcn_mfma_f32_16x16x32_bf16(a, b, d, 0, 0, 0)

template<bool EPI>
__global__ __launch_bounds__(256, 3) void gemm_kernel(
    const unsigned short* __restrict__ A,
    const unsigned short* __restrict__ Bt,
    const float* __restrict__ bias,
    void* __restrict__ C,
    const unsigned short* __restrict__ resid,
    int M, int Ncols)
{
    __shared__ unsigned short As[128 * 32];   // 8 KB
    __shared__ unsigned short Bs[128 * 32];   // 8 KB
    int tid  = threadIdx.x;
    int wave = tid >> 6, lane = tid & 63;
    int quad = lane >> 4, l16 = lane & 15;
    int m0 = blockIdx.x * 128, n0 = blockIdx.y * 128;
    int wm = (wave >> 1) * 64, wn = (wave & 1) * 64;

    // staging: thread t covers LDS row t>>2 (and +64), 16B chunk (t&3) of the 64B k-slice
    int r0 = tid >> 2;                // 0..63
    int cb = (tid & 3) * 8;           // shorts
    int arow0 = m0 + r0;      if (arow0 >= M) arow0 = M - 1;   // tail dup, discarded
    int arow1 = m0 + 64 + r0; if (arow1 >= M) arow1 = M - 1;
    const unsigned short* Ag0 = A  + (size_t)arow0 * 256 + cb;
    const unsigned short* Ag1 = A  + (size_t)arow1 * 256 + cb;
    const unsigned short* Bg0 = Bt + (size_t)(n0 + r0) * 256 + cb;
    const unsigned short* Bg1 = Bt + (size_t)(n0 + 64 + r0) * 256 + cb;
    unsigned short* AsW = As + wave * 512;    // wave-uniform LDS bases (shorts)
    unsigned short* BsW = Bs + wave * 512;

    f32x4 acc00 = {}, acc01 = {}, acc02 = {}, acc03 = {};
    f32x4 acc10 = {}, acc11 = {}, acc12 = {}, acc13 = {};
    f32x4 acc20 = {}, acc21 = {}, acc22 = {}, acc23 = {};
    f32x4 acc30 = {}, acc31 = {}, acc32 = {}, acc33 = {};

    for (int kt = 0; kt < 8; ++kt) {          // K=256, BK=32
        __syncthreads();                      // prior ds_reads done before DMA overwrite
        async16(Ag0 + kt * 32, AsW);
        async16(Ag1 + kt * 32, AsW + 2048);
        async16(Bg0 + kt * 32, BsW);
        async16(Bg1 + kt * 32, BsW + 2048);
        __syncthreads();                      // drains vmcnt(0): DMA complete
        bf16x8 a0 = *(const bf16x8*)&As[(wm +  0 + l16) * 32 + quad * 8];
        bf16x8 a1 = *(const bf16x8*)&As[(wm + 16 + l16) * 32 + quad * 8];
        bf16x8 a2 = *(const bf16x8*)&As[(wm + 32 + l16) * 32 + quad * 8];
        bf16x8 a3 = *(const bf16x8*)&As[(wm + 48 + l16) * 32 + quad * 8];
        bf16x8 b0 = *(const bf16x8*)&Bs[(wn +  0 + l16) * 32 + quad * 8];
        bf16x8 b1 = *(const bf16x8*)&Bs[(wn + 16 + l16) * 32 + quad * 8];
        bf16x8 b2 = *(const bf16x8*)&Bs[(wn + 32 + l16) * 32 + quad * 8];
        bf16x8 b3 = *(const bf16x8*)&Bs[(wn + 48 + l16) * 32 + quad * 8];
        MFMA_BF16(acc00, a0, b0); MFMA_BF16(acc01, a0, b1);
        MFMA_BF16(acc02, a0, b2); MFMA_BF16(acc03, a0, b3);
        MFMA_BF16(acc10, a1, b0); MFMA_BF16(acc11, a1, b1);
        MFMA_BF16(acc12, a1, b2); MFMA_BF16(acc13, a1, b3);
        MFMA_BF16(acc20, a2, b0); MFMA_BF16(acc21, a2, b1);
        MFMA_BF16(acc22, a2, b2); MFMA_BF16(acc23, a2, b3);
        MFMA_BF16(acc30, a3, b0); MFMA_BF16(acc31, a3, b1);
        MFMA_BF16(acc32, a3, b2); MFMA_BF16(acc33, a3, b3);
    }

#define EPI_STORE(accv, R, CC) do {                                          \
        int col = n0 + wn + (CC) * 16 + l16;                                 \
        float bb = bias[col];                                                \
        int rowb = m0 + wm + (R) * 16 + quad * 4;                            \
        _Pragma("unroll")                                                    \
        for (int rr = 0; rr < 4; ++rr) {                                     \
            int row = rowb + rr;                                             \
            if (row < M) {                                                   \
                float v = (accv)[rr] + bb;                                   \
                if (EPI) {                                                   \
                    v = fmaxf(v, 0.f);                                       \
                    v += bf2f(resid[(size_t)row * 256 + col]);               \
                    ((float*)C)[(size_t)row * Ncols + col] = v;              \
                } else {                                                     \
                    ((unsigned short*)C)[(size_t)row * Ncols + col] = f2bf(v);\
                }                                                            \
            }                                                                \
        }                                                                    \
    } while (0)

    EPI_STORE(acc00, 0, 0); EPI_STORE(acc01, 0, 1); EPI_STORE(acc02, 0, 2); EPI_STORE(acc03, 0, 3);
    EPI_STORE(acc10, 1, 0); EPI_STORE(acc11, 1, 1); EPI_STORE(acc12, 1, 2); EPI_STORE(acc13, 1, 3);
    EPI_STORE(acc20, 2, 0); EPI_STORE(acc21, 2, 1); EPI_STORE(acc22, 2, 2); EPI_STORE(acc23, 2, 3);
    EPI_STORE(acc30, 3, 0); EPI_STORE(acc31, 3, 1); EPI_STORE(acc32, 3, 2); EPI_STORE(acc33, 3, 3);
#undef EPI_STORE
}

// ---------- K3: edge attention + residual + LN2 — wave = node, half-wave = batch ----------
// Prefetch ALL 8 neighbors' K and V into named registers first (16 loads in flight),
// then compute — attacks the latency-bound profile (R8: VALUBusy 29%, HBM 47%).
__global__ __launch_bounds__(256) void attn_kernel(
    const unsigned short* __restrict__ qkv,   // [ROWS][768] bf16: q|k|v
    const int* __restrict__ edges,            // int32 [E][2]
    const unsigned short* __restrict__ xn,    // [ROWS][256] bf16
    const float* __restrict__ g2, const float* __restrict__ b2,
    unsigned short* __restrict__ concat,      // [ROWS][256] bf16
    unsigned short* __restrict__ h2)          // [ROWS][256] bf16
{
    int wave = threadIdx.x >> 6, lane = threadIdx.x & 63;
    int i = blockIdx.x * 4 + wave;            // node id
    int b = lane >> 5, hl = lane & 31;        // batch half, 8 dims/lane
    size_t m = (size_t)b * NNODE + i;

    int4 qi = *(const int4*)(qkv + m * 768 + hl * 8);
    const unsigned short* qs = (const unsigned short*)&qi;
    float qf[8];
    #pragma unroll
    for (int t = 0; t < 8; ++t) qf[t] = bf2f(qs[t]);

    int jv = 0;
    if (lane < 8) jv = edges[2 * (i * 8 + lane) + 1];   // int32 dst of edge

#define KVLOAD(E)                                                                  \
    int j##E = __shfl(jv, E);                                                      \
    const unsigned short* kp##E = qkv + ((size_t)b * NNODE + j##E) * 768 + 256 + hl * 8; \
    int4 KI##E = *(const int4*)(kp##E);                                            \
    int4 VI##E = *(const int4*)(kp##E + 256);
    KVLOAD(0) KVLOAD(1) KVLOAD(2) KVLOAD(3)
    KVLOAD(4) KVLOAD(5) KVLOAD(6) KVLOAD(7)
#undef KVLOAD

    float acc[8] = {};
    float den = 0.f;
    const float scale = 0.17677669529663687f;           // 1/sqrt(32)
#define EDGE(E) do {                                                         \
        const unsigned short* ks = (const unsigned short*)&KI##E;            \
        const unsigned short* vs = (const unsigned short*)&VI##E;            \
        float dot = 0.f;                                                     \
        _Pragma("unroll")                                                    \
        for (int t = 0; t < 8; ++t) dot += qf[t] * bf2f(ks[t]);              \
        dot += __shfl_xor(dot, 1);                                           \
        dot += __shfl_xor(dot, 2);            /* head = 4 lanes (dh=32) */   \
        float w = __expf(dot * scale);                                       \
        _Pragma("unroll")                                                    \
        for (int t = 0; t < 8; ++t) acc[t] += w * bf2f(vs[t]);               \
        den += w;                                                            \
    } while (0)
    EDGE(0); EDGE(1); EDGE(2); EDGE(3);
    EDGE(4); EDGE(5); EDGE(6); EDGE(7);
#undef EDGE
    float inv = 1.f / den;

    int4 xi = *(const int4*)(xn + m * DMODEL + hl * 8);
    const unsigned short* xs = (const unsigned short*)&xi;
    float c[8], s = 0.f, ss = 0.f;
    #pragma unroll
    for (int t = 0; t < 8; ++t) { c[t] = bf2f(xs[t]) + acc[t] * inv; s += c[t]; ss += c[t]*c[t]; }
    #pragma unroll
    for (int mk = 1; mk < 32; mk <<= 1) { s += __shfl_xor(s, mk); ss += __shfl_xor(ss, mk); }
    float mu  = s * (1.f/256.f);
    float var = ss * (1.f/256.f) - mu*mu;
    float rs  = rsqrtf(var + 1e-3f);

    float4 ga = *(const float4*)(g2 + hl * 8);
    float4 gb = *(const float4*)(g2 + hl * 8 + 4);
    float4 ba = *(const float4*)(b2 + hl * 8);
    float4 bb = *(const float4*)(b2 + hl * 8 + 4);
    float gg[8] = {ga.x, ga.y, ga.z, ga.w, gb.x, gb.y, gb.z, gb.w};
    float bv[8] = {ba.x, ba.y, ba.z, ba.w, bb.x, bb.y, bb.z, bb.w};
    unsigned short oc[8], oh[8];
    #pragma unroll
    for (int t = 0; t < 8; ++t) {
        oc[t] = f2bf(c[t]);
        oh[t] = f2bf((c[t] - mu) * rs * gg[t] + bv[t]);
    }
    *(int4*)(concat + m * DMODEL + hl * 8) = *(const int4*)oc;
    *(int4*)(h2     + m * DMODEL + hl * 8) = *(const int4*)oh;
}

// ---------- launch ----------
extern "C" void kernel_launch(void* const* d_in, const int* in_sizes, int n_in,
                              void* d_out, int out_size, void* d_ws, size_t ws_size,
                              hipStream_t stream)
{
    const float* x   = (const float*)d_in[0];
    const int* edges = (const int*)d_in[1];
    const float* wq = (const float*)d_in[2];
    const float* bq = (const float*)d_in[3];
    const float* wk = (const float*)d_in[4];
    const float* bk = (const float*)d_in[5];
    const float* wv = (const float*)d_in[6];
    const float* bv = (const float*)d_in[7];
    const float* wo = (const float*)d_in[8];
    const float* bo = (const float*)d_in[9];
    const float* g1 = (const float*)d_in[10];
    const float* b1 = (const float*)d_in[11];
    const float* g2 = (const float*)d_in[12];
    const float* b2 = (const float*)d_in[13];

    char* ws = (char*)d_ws;
    unsigned short* Wqkvt = (unsigned short*)(ws);                    // 393216 B
    unsigned short* Wot   = (unsigned short*)(ws + 393216);           // 131072 B
    float* biasq          = (float*)(ws + 393216 + 131072);           // 3072 B
    float* biaso          = (float*)(ws + 393216 + 131072 + 3072);    // 1024 B
    size_t off = 393216 + 131072 + 4096;
    unsigned short* xn     = (unsigned short*)(ws + off); off += (size_t)ROWS * DMODEL * 2;
    unsigned short* qkv    = (unsigned short*)(ws + off); off += (size_t)ROWS * 768 * 2;
    unsigned short* concat = (unsigned short*)(ws + off); off += (size_t)ROWS * DMODEL * 2;
    unsigned short* h2     = (unsigned short*)(ws + off); off += (size_t)ROWS * DMODEL * 2;

    prep_kernel<<<1024, 256, 0, stream>>>(wq, wk, wv, wo, bq, bk, bv, bo, Wqkvt, Wot, biasq, biaso);
    ln1_kernel<<<ROWS / 8, 256, 0, stream>>>(x, g1, b1, xn);
    gemm_kernel<false><<<dim3(313, 6), 256, 0, stream>>>(xn, Wqkvt, biasq, qkv, nullptr, ROWS, 768);
    attn_kernel<<<NNODE / 4, 256, 0, stream>>>(qkv, edges, xn, g2, b2, concat, h2);
    gemm_kernel<true><<<dim3(313, 2), 256, 0, stream>>>(h2, Wot, biaso, d_out, concat, ROWS, 256);
}

// Round 10
// 236.797 us; speedup vs baseline: 1.4758x; 1.4758x over previous
//
#include <hip/hip_runtime.h>

// Dtypes (R1-R6 forensics): floats fp32, edges int32 [E][2], output fp32.
// Workspace intermediates: bf16 (MFMA path).
// Spill law (R6-R9): GEMM per-wave reg demand ~200 -> needs (256,2) budget (256/wave).
//   (256,3) splits 84 arch + 84 acc -> hot-loop spill (MfmaUtil 4.5%, WRITE 3-5x output).
//   Local arrays with MFMA also force scratch regardless of budget. Named scalars + (256,2).
// global_load_lds staging: regressed twice (R9) under this structure -- do not reintroduce
// without isolated probe.

typedef __bf16 bf16x8 __attribute__((ext_vector_type(8)));
typedef float  f32x4  __attribute__((ext_vector_type(4)));

__device__ __forceinline__ float bf2f(unsigned short u) {
    union { unsigned int i; float f; } v; v.i = ((unsigned int)u) << 16; return v.f;
}
__device__ __forceinline__ unsigned short f2bf(float f) {
    union { float f; unsigned int i; } v; v.f = f;
    unsigned int x = v.i;
    unsigned int r = (x + 0x7FFFu + ((x >> 16) & 1u)) >> 16;   // RNE
    return (unsigned short)r;
}

#define NNODE 20000
#define ROWS  40000      // B*N
#define DMODEL 256

// ---------- K0: fused prep (blocks 0..1023) + LayerNorm1 (blocks 1024..6023) ----------
__global__ __launch_bounds__(256) void prep_ln1_kernel(
    const float* __restrict__ wq, const float* __restrict__ wk,
    const float* __restrict__ wv, const float* __restrict__ wo,
    const float* __restrict__ bq, const float* __restrict__ bk,
    const float* __restrict__ bv, const float* __restrict__ bo,
    const float* __restrict__ x,
    const float* __restrict__ g1, const float* __restrict__ b1,
    unsigned short* __restrict__ Wqkvt,   // [768][256] bf16
    unsigned short* __restrict__ Wot,     // [256][256] bf16
    float* __restrict__ biasq,            // [768]
    float* __restrict__ biaso,            // [256]
    unsigned short* __restrict__ xn)      // [ROWS][256] bf16
{
    if (blockIdx.x < 1024) {
        int idx = blockIdx.x * 256 + threadIdx.x;
        if (idx < 768 * 256) {
            int n = idx >> 8, k = idx & 255;
            int sel = n >> 8, nl = n & 255;
            const float* w = (sel == 0) ? wq : (sel == 1) ? wk : wv;
            Wqkvt[idx] = f2bf(w[k * 256 + nl]);
        } else {
            int idx2 = idx - 768 * 256;        // [0, 65536)
            int n = idx2 >> 8, k = idx2 & 255;
            Wot[idx2] = f2bf(wo[k * 256 + n]);
        }
        if (idx < 768) {
            const float* bb = (idx < 256) ? bq : (idx < 512) ? bk : bv;
            biasq[idx] = bb[idx & 255];
        }
        if (idx >= 768 && idx < 1024) biaso[idx - 768] = bo[idx - 768];
        return;
    }
    // ---- LN1: half-wave (32 lanes) per row, 8 elems/lane ----
    int wave = threadIdx.x >> 6, lane = threadIdx.x & 63;
    int sub = lane >> 5, hl = lane & 31;
    int m = (blockIdx.x - 1024) * 8 + wave * 2 + sub;
    const float* xp = x + (size_t)m * DMODEL + hl * 8;
    float4 x0 = *(const float4*)xp;
    float4 x1 = *(const float4*)(xp + 4);
    float f[8] = {x0.x, x0.y, x0.z, x0.w, x1.x, x1.y, x1.z, x1.w};
    float s = 0.f, ss = 0.f;
    #pragma unroll
    for (int t = 0; t < 8; ++t) { s += f[t]; ss += f[t]*f[t]; }
    #pragma unroll
    for (int mk = 1; mk < 32; mk <<= 1) { s += __shfl_xor(s, mk); ss += __shfl_xor(ss, mk); }
    float mu  = s * (1.f/256.f);
    float var = ss * (1.f/256.f) - mu*mu;
    float rs  = rsqrtf(var + 1e-3f);
    float4 g0 = *(const float4*)(g1 + hl * 8);
    float4 g1v = *(const float4*)(g1 + hl * 8 + 4);
    float4 b0 = *(const float4*)(b1 + hl * 8);
    float4 b1v = *(const float4*)(b1 + hl * 8 + 4);
    float gg[8] = {g0.x, g0.y, g0.z, g0.w, g1v.x, g1v.y, g1v.z, g1v.w};
    float bb[8] = {b0.x, b0.y, b0.z, b0.w, b1v.x, b1v.y, b1v.z, b1v.w};
    unsigned short o[8];
    #pragma unroll
    for (int t = 0; t < 8; ++t) o[t] = f2bf((f[t] - mu) * rs * gg[t] + bb[t]);
    *(int4*)(xn + (size_t)m * DMODEL + hl * 8) = *(const int4*)o;
}

// ---------- K2/K4: bf16 MFMA GEMM, 128x128 tile, BK=64, VGPR-staged LDS (R8-proven) ----------
// C = A[M][256] @ Bt[Ncols][256]^T + bias.  EPI: relu + resid, write fp32; else bf16.
#define LDS_W 72   // 64 + 8 pad -> 144B row stride, ~2-way bank alias (free per m136)
#define MFMA_BF16(d, a, b) d = __builtin_amdgcn_mfma_f32_16x16x32_bf16(a, b, d, 0, 0, 0)

template<bool EPI>
__global__ __launch_bounds__(256, 2) void gemm_kernel(
    const unsigned short* __restrict__ A,
    const unsigned short* __restrict__ Bt,
    const float* __restrict__ bias,
    void* __restrict__ C,
    const unsigned short* __restrict__ resid,
    int M, int Ncols)
{
    __shared__ unsigned short As[128 * LDS_W];
    __shared__ unsigned short Bs[128 * LDS_W];
    int tid  = threadIdx.x;
    int wave = tid >> 6, lane = tid & 63;
    int quad = lane >> 4, l16 = lane & 15;
    int m0 = blockIdx.x * 128, n0 = blockIdx.y * 128;
    int wm = (wave >> 1) * 64, wn = (wave & 1) * 64;

    int srow = tid >> 1;            // 0..127
    int sseg = (tid & 1) * 32;      // half of the 64-short k-slice
    int arow = m0 + srow; if (arow >= M) arow = M - 1;   // tail dup, discarded
    const unsigned short* ArowP = A  + (size_t)arow * 256 + sseg;
    const unsigned short* BrowP = Bt + (size_t)(n0 + srow) * 256 + sseg;
    unsigned short* AsP = &As[srow * LDS_W + sseg];
    unsigned short* BsP = &Bs[srow * LDS_W + sseg];

    f32x4 acc00 = {}, acc01 = {}, acc02 = {}, acc03 = {};
    f32x4 acc10 = {}, acc11 = {}, acc12 = {}, acc13 = {};
    f32x4 acc20 = {}, acc21 = {}, acc22 = {}, acc23 = {};
    f32x4 acc30 = {}, acc31 = {}, acc32 = {}, acc33 = {};

    for (int kt = 0; kt < 4; ++kt) {            // K=256, BK=64
        const unsigned short* ap = ArowP + kt * 64;
        const unsigned short* bp = BrowP + kt * 64;
        int4 va0 = *(const int4*)(ap);
        int4 va1 = *(const int4*)(ap + 8);
        int4 va2 = *(const int4*)(ap + 16);
        int4 va3 = *(const int4*)(ap + 24);
        int4 vb0 = *(const int4*)(bp);
        int4 vb1 = *(const int4*)(bp + 8);
        int4 vb2 = *(const int4*)(bp + 16);
        int4 vb3 = *(const int4*)(bp + 24);
        __syncthreads();                        // prior ds_reads done before overwrite
        *(int4*)(AsP)      = va0;
        *(int4*)(AsP + 8)  = va1;
        *(int4*)(AsP + 16) = va2;
        *(int4*)(AsP + 24) = va3;
        *(int4*)(BsP)      = vb0;
        *(int4*)(BsP + 8)  = vb1;
        *(int4*)(BsP + 16) = vb2;
        *(int4*)(BsP + 24) = vb3;
        __syncthreads();
        #pragma unroll
        for (int ks = 0; ks < 64; ks += 32) {   // two 32-wide K steps
            bf16x8 a0 = *(const bf16x8*)&As[(wm +  0 + l16) * LDS_W + ks + quad * 8];
            bf16x8 a1 = *(const bf16x8*)&As[(wm + 16 + l16) * LDS_W + ks + quad * 8];
            bf16x8 a2 = *(const bf16x8*)&As[(wm + 32 + l16) * LDS_W + ks + quad * 8];
            bf16x8 a3 = *(const bf16x8*)&As[(wm + 48 + l16) * LDS_W + ks + quad * 8];
            bf16x8 b0 = *(const bf16x8*)&Bs[(wn +  0 + l16) * LDS_W + ks + quad * 8];
            bf16x8 b1 = *(const bf16x8*)&Bs[(wn + 16 + l16) * LDS_W + ks + quad * 8];
            bf16x8 b2 = *(const bf16x8*)&Bs[(wn + 32 + l16) * LDS_W + ks + quad * 8];
            bf16x8 b3 = *(const bf16x8*)&Bs[(wn + 48 + l16) * LDS_W + ks + quad * 8];
            MFMA_BF16(acc00, a0, b0); MFMA_BF16(acc01, a0, b1);
            MFMA_BF16(acc02, a0, b2); MFMA_BF16(acc03, a0, b3);
            MFMA_BF16(acc10, a1, b0); MFMA_BF16(acc11, a1, b1);
            MFMA_BF16(acc12, a1, b2); MFMA_BF16(acc13, a1, b3);
            MFMA_BF16(acc20, a2, b0); MFMA_BF16(acc21, a2, b1);
            MFMA_BF16(acc22, a2, b2); MFMA_BF16(acc23, a2, b3);
            MFMA_BF16(acc30, a3, b0); MFMA_BF16(acc31, a3, b1);
            MFMA_BF16(acc32, a3, b2); MFMA_BF16(acc33, a3, b3);
        }
    }

#define EPI_STORE(accv, R, CC) do {                                          \
        int col = n0 + wn + (CC) * 16 + l16;                                 \
        float bb = bias[col];                                                \
        int rowb = m0 + wm + (R) * 16 + quad * 4;                            \
        _Pragma("unroll")                                                    \
        for (int rr = 0; rr < 4; ++rr) {                                     \
            int row = rowb + rr;                                             \
            if (row < M) {                                                   \
                float v = (accv)[rr] + bb;                                   \
                if (EPI) {                                                   \
                    v = fmaxf(v, 0.f);                                       \
                    v += bf2f(resid[(size_t)row * 256 + col]);               \
                    ((float*)C)[(size_t)row * Ncols + col] = v;              \
                } else {                                                     \
                    ((unsigned short*)C)[(size_t)row * Ncols + col] = f2bf(v);\
                }                                                            \
            }                                                                \
        }                                                                    \
    } while (0)

    EPI_STORE(acc00, 0, 0); EPI_STORE(acc01, 0, 1); EPI_STORE(acc02, 0, 2); EPI_STORE(acc03, 0, 3);
    EPI_STORE(acc10, 1, 0); EPI_STORE(acc11, 1, 1); EPI_STORE(acc12, 1, 2); EPI_STORE(acc13, 1, 3);
    EPI_STORE(acc20, 2, 0); EPI_STORE(acc21, 2, 1); EPI_STORE(acc22, 2, 2); EPI_STORE(acc23, 2, 3);
    EPI_STORE(acc30, 3, 0); EPI_STORE(acc31, 3, 1); EPI_STORE(acc32, 3, 2); EPI_STORE(acc33, 3, 3);
#undef EPI_STORE
}

// ---------- K3: edge attention + residual + LN2 — wave = node, half-wave = batch ----------
// All 16 K/V gather loads issued into named registers before compute (R9; no spill: WRITE 41MB clean).
__global__ __launch_bounds__(256) void attn_kernel(
    const unsigned short* __restrict__ qkv,   // [ROWS][768] bf16: q|k|v
    const int* __restrict__ edges,            // int32 [E][2]
    const unsigned short* __restrict__ xn,    // [ROWS][256] bf16
    const float* __restrict__ g2, const float* __restrict__ b2,
    unsigned short* __restrict__ concat,      // [ROWS][256] bf16
    unsigned short* __restrict__ h2)          // [ROWS][256] bf16
{
    int wave = threadIdx.x >> 6, lane = threadIdx.x & 63;
    int i = blockIdx.x * 4 + wave;            // node id
    int b = lane >> 5, hl = lane & 31;        // batch half, 8 dims/lane
    size_t m = (size_t)b * NNODE + i;

    int4 qi = *(const int4*)(qkv + m * 768 + hl * 8);
    const unsigned short* qs = (const unsigned short*)&qi;
    float qf[8];
    #pragma unroll
    for (int t = 0; t < 8; ++t) qf[t] = bf2f(qs[t]);

    int jv = 0;
    if (lane < 8) jv = edges[2 * (i * 8 + lane) + 1];   // int32 dst of edge

#define KVLOAD(E)                                                                  \
    int j##E = __shfl(jv, E);                                                      \
    const unsigned short* kp##E = qkv + ((size_t)b * NNODE + j##E) * 768 + 256 + hl * 8; \
    int4 KI##E = *(const int4*)(kp##E);                                            \
    int4 VI##E = *(const int4*)(kp##E + 256);
    KVLOAD(0) KVLOAD(1) KVLOAD(2) KVLOAD(3)
    KVLOAD(4) KVLOAD(5) KVLOAD(6) KVLOAD(7)
#undef KVLOAD

    float acc[8] = {};
    float den = 0.f;
    const float scale = 0.17677669529663687f;           // 1/sqrt(32)
#define EDGE(E) do {                                                         \
        const unsigned short* ks = (const unsigned short*)&KI##E;            \
        const unsigned short* vs = (const unsigned short*)&VI##E;            \
        float dot = 0.f;                                                     \
        _Pragma("unroll")                                                    \
        for (int t = 0; t < 8; ++t) dot += qf[t] * bf2f(ks[t]);              \
        dot += __shfl_xor(dot, 1);                                           \
        dot += __shfl_xor(dot, 2);            /* head = 4 lanes (dh=32) */   \
        float w = __expf(dot * scale);                                       \
        _Pragma("unroll")                                                    \
        for (int t = 0; t < 8; ++t) acc[t] += w * bf2f(vs[t]);               \
        den += w;                                                            \
    } while (0)
    EDGE(0); EDGE(1); EDGE(2); EDGE(3);
    EDGE(4); EDGE(5); EDGE(6); EDGE(7);
#undef EDGE
    float inv = 1.f / den;

    int4 xi = *(const int4*)(xn + m * DMODEL + hl * 8);
    const unsigned short* xs = (const unsigned short*)&xi;
    float c[8], s = 0.f, ss = 0.f;
    #pragma unroll
    for (int t = 0; t < 8; ++t) { c[t] = bf2f(xs[t]) + acc[t] * inv; s += c[t]; ss += c[t]*c[t]; }
    #pragma unroll
    for (int mk = 1; mk < 32; mk <<= 1) { s += __shfl_xor(s, mk); ss += __shfl_xor(ss, mk); }
    float mu  = s * (1.f/256.f);
    float var = ss * (1.f/256.f) - mu*mu;
    float rs  = rsqrtf(var + 1e-3f);

    float4 ga = *(const float4*)(g2 + hl * 8);
    float4 gb = *(const float4*)(g2 + hl * 8 + 4);
    float4 ba = *(const float4*)(b2 + hl * 8);
    float4 bb = *(const float4*)(b2 + hl * 8 + 4);
    float gg[8] = {ga.x, ga.y, ga.z, ga.w, gb.x, gb.y, gb.z, gb.w};
    float bv[8] = {ba.x, ba.y, ba.z, ba.w, bb.x, bb.y, bb.z, bb.w};
    unsigned short oc[8], oh[8];
    #pragma unroll
    for (int t = 0; t < 8; ++t) {
        oc[t] = f2bf(c[t]);
        oh[t] = f2bf((c[t] - mu) * rs * gg[t] + bv[t]);
    }
    *(int4*)(concat + m * DMODEL + hl * 8) = *(const int4*)oc;
    *(int4*)(h2     + m * DMODEL + hl * 8) = *(const int4*)oh;
}

// ---------- launch ----------
extern "C" void kernel_launch(void* const* d_in, const int* in_sizes, int n_in,
                              void* d_out, int out_size, void* d_ws, size_t ws_size,
                              hipStream_t stream)
{
    const float* x   = (const float*)d_in[0];
    const int* edges = (const int*)d_in[1];
    const float* wq = (const float*)d_in[2];
    const float* bq = (const float*)d_in[3];
    const float* wk = (const float*)d_in[4];
    const float* bk = (const float*)d_in[5];
    const float* wv = (const float*)d_in[6];
    const float* bv = (const float*)d_in[7];
    const float* wo = (const float*)d_in[8];
    const float* bo = (const float*)d_in[9];
    const float* g1 = (const float*)d_in[10];
    const float* b1 = (const float*)d_in[11];
    const float* g2 = (const float*)d_in[12];
    const float* b2 = (const float*)d_in[13];

    char* ws = (char*)d_ws;
    unsigned short* Wqkvt = (unsigned short*)(ws);                    // 393216 B
    unsigned short* Wot   = (unsigned short*)(ws + 393216);           // 131072 B
    float* biasq          = (float*)(ws + 393216 + 131072);           // 3072 B
    float* biaso          = (float*)(ws + 393216 + 131072 + 3072);    // 1024 B
    size_t off = 393216 + 131072 + 4096;
    unsigned short* xn     = (unsigned short*)(ws + off); off += (size_t)ROWS * DMODEL * 2;
    unsigned short* qkv    = (unsigned short*)(ws + off); off += (size_t)ROWS * 768 * 2;
    unsigned short* concat = (unsigned short*)(ws + off); off += (size_t)ROWS * DMODEL * 2;
    unsigned short* h2     = (unsigned short*)(ws + off); off += (size_t)ROWS * DMODEL * 2;

    prep_ln1_kernel<<<1024 + ROWS / 8, 256, 0, stream>>>(
        wq, wk, wv, wo, bq, bk, bv, bo, x, g1, b1, Wqkvt, Wot, biasq, biaso, xn);
    gemm_kernel<false><<<dim3(313, 6), 256, 0, stream>>>(xn, Wqkvt, biasq, qkv, nullptr, ROWS, 768);
    attn_kernel<<<NNODE / 4, 256, 0, stream>>>(qkv, edges, xn, g2, b2, concat, h2);
    gemm_kernel<true><<<dim3(313, 2), 256, 0, stream>>>(h2, Wot, biaso, d_out, concat, ROWS, 256);
}